// Round 4
// baseline (546.775 us; speedup 1.0000x reference)
//
#include <hip/hip_runtime.h>

typedef __bf16 bf16x8 __attribute__((ext_vector_type(8)));
typedef __bf16 bf16x4 __attribute__((ext_vector_type(4)));
typedef float  f32x4  __attribute__((ext_vector_type(4)));

__device__ __forceinline__ f32x4 mfma_bf16(bf16x8 a, bf16x8 b, f32x4 c) {
  return __builtin_amdgcn_mfma_f32_16x16x32_bf16(a, b, c, 0, 0, 0);
}
// Packed B-fragment load: Bp[((kt*NT+nt)*64+lane)*8 .. +7]
__device__ __forceinline__ bf16x8 ldB(const __bf16* Bp, int kt, int NT, int nt,
                                      int lane) {
  return *reinterpret_cast<const bf16x8*>(Bp + (((size_t)kt * NT + nt) * 64 + lane) * 8);
}

// Grid barrier: monotonic counter, all blocks resident by construction.
// Release: __threadfence (wbl2) + release RMW. Spin: RELAXED loads (no cache
// maintenance -> no L2 thrash for still-working blocks). Acquire: __threadfence
// (inv) after spin exit. Counter zeroed per kernel_launch via hipMemsetAsync.
__device__ __forceinline__ void gridbar(int* cnt, int target) {
  __syncthreads();
  if (threadIdx.x == 0) {
    __threadfence();
    __hip_atomic_fetch_add(cnt, 1, __ATOMIC_RELEASE, __HIP_MEMORY_SCOPE_AGENT);
    while (__hip_atomic_load(cnt, __ATOMIC_RELAXED, __HIP_MEMORY_SCOPE_AGENT) < target)
      __builtin_amdgcn_s_sleep(4);
    __threadfence();
  }
  __syncthreads();
}

// 64x64-tile f32 GEMM body, 256 active threads of a 512-thr block.
__device__ void small_body(char* SM, int t,
                           const float* __restrict__ A, const float* __restrict__ A2,
                           int lda, const float* __restrict__ Bm, int ldb,
                           float* __restrict__ C, int ldc,
                           int M, int N, int K, int m0, int n0) {
  float (*As)[17] = (float(*)[17])SM;
  float (*Bs)[65] = (float(*)[65])(SM + 4352);
  bool act = t < 256;
  int tx = t & 15, ty = (t >> 4) & 15;
  float acc[4][4] = {};
  for (int k0 = 0; k0 < K; k0 += 16) {
    if (act) {
#pragma unroll
      for (int i = 0; i < 4; ++i) {
        int idx = t * 4 + i;
        int r = idx >> 4, kk = idx & 15;
        int gm = m0 + r, gk = k0 + kk;
        float v = (gm < M && gk < K) ? A[(size_t)gm * lda + gk] : 0.f;
        if (A2 && gm < M && gk < K) v *= A2[(size_t)gm * lda + gk];
        As[r][kk] = v;
        int kk2 = idx >> 6, cc = idx & 63;
        int gk2 = k0 + kk2, gn = n0 + cc;
        Bs[kk2][cc] = (gk2 < K && gn < N) ? Bm[(size_t)gk2 * ldb + gn] : 0.f;
      }
    }
    __syncthreads();
    if (act) {
#pragma unroll
      for (int kk = 0; kk < 16; ++kk)
#pragma unroll
        for (int i = 0; i < 4; ++i)
#pragma unroll
          for (int j = 0; j < 4; ++j)
            acc[i][j] += As[ty * 4 + i][kk] * Bs[kk][tx * 4 + j];
    }
    __syncthreads();
  }
  if (act) {
#pragma unroll
    for (int i = 0; i < 4; ++i)
#pragma unroll
      for (int j = 0; j < 4; ++j) {
        int gm = m0 + ty * 4 + i, gn = n0 + tx * 4 + j;
        if (gm < M && gn < N) C[(size_t)gm * ldc + gn] = acc[i][j];
      }
  }
}

// ---------------------------------------------------------------------------
// mega1: P0 pack+zeroG | P1 h1h2 | P2 masks||g1zgeo | P3a T | P3b ec
// grid 512 x 512 thr; residency: VGPR<=128 (launch_bounds), LDS 38.9KB -> 2/CU
// ---------------------------------------------------------------------------
__global__ __launch_bounds__(512, 4) void mega1(
    const float* __restrict__ x,
    const float* __restrict__ W1, const float* __restrict__ b1,
    const float* __restrict__ W2, const float* __restrict__ b2,
    const float* __restrict__ W3, const float* __restrict__ mc,
    const float* __restrict__ Wg1, const float* __restrict__ bg1,
    const float* __restrict__ Wg2, const float* __restrict__ bg2,
    const float* __restrict__ Wr1, const float* __restrict__ Wr2,
    __bf16* __restrict__ W1p, __bf16* __restrict__ W2p,
    __bf16* __restrict__ Wg1p, __bf16* __restrict__ Wg2p,
    __bf16* __restrict__ Wr1p, __bf16* __restrict__ Wr2p,
    __bf16* __restrict__ m1T, __bf16* __restrict__ m2T,
    float* __restrict__ G, float* __restrict__ T,
    float* __restrict__ o_zgeo, float* __restrict__ o_ec,
    int* __restrict__ cnt) {
  __shared__ __align__(16) char SM[38912];
  int tid = threadIdx.x, bid = blockIdx.x;
  int lane = tid & 63, wid = tid >> 6;
  int q4 = (lane >> 4) * 4;

  // ---- P0: pack weights (1104 groups of 64 lanes) + zero G (32 groups) ----
  {
    int gid = bid * 8 + wid;
    if (gid < 1104) {
      const float* W; __bf16* outp; int N, K, NT, local;
      if (gid < 544)      { W = W1;  outp = W1p;  N = 256; K = 1080; NT = 16; local = gid; }
      else if (gid < 672) { W = W2;  outp = W2p;  N = 256; K = 256;  NT = 16; local = gid - 544; }
      else if (gid < 784) { W = Wg1; outp = Wg1p; N = 256; K = 200;  NT = 16; local = gid - 672; }
      else if (gid < 848) { W = Wg2; outp = Wg2p; N = 128; K = 256;  NT = 8;  local = gid - 784; }
      else if (gid < 912) { W = Wr1; outp = Wr1p; N = 256; K = 128;  NT = 16; local = gid - 848; }
      else                { W = Wr2; outp = Wr2p; N = 360; K = 256;  NT = 24; local = gid - 912; }
      int nt = local % NT, kt = local / NT;
      int n = nt * 16 + (lane & 15);
      int k0 = kt * 32 + (lane >> 4) * 8;
      bf16x8 v;
#pragma unroll
      for (int e = 0; e < 8; ++e) {
        int k = k0 + e;
        float xv = (n < N && k < K) ? W[(size_t)n * K + k] : 0.f;
        v[e] = (__bf16)xv;
      }
      *reinterpret_cast<bf16x8*>(outp + ((size_t)local * 64 + lane) * 8) = v;
    } else if (gid < 1136) {
      float4* g = (float4*)G;
      int base = (gid - 1104) * 512 + lane;
#pragma unroll
      for (int i = 0; i < 8; ++i) g[base + i * 64] = make_float4(0.f, 0.f, 0.f, 0.f);
    }
  }
  gridbar(cnt, 512);

  // ---- P1: h1h2 fused, tile 32 rows, 8 waves (1m x 4n per wave) ----
  {
    __bf16 (*Alds)[68] = (__bf16(*)[68])SM;
    __bf16 (*h1s)[264] = (__bf16(*)[264])(SM + 4352);
    int wr16 = (wid >> 2) * 16, wc4 = (wid & 3) * 4, wc64 = (wid & 3) * 64;
    int rowBase = bid * 32;
    int sr = tid >> 4, sc = (tid & 15) * 4;
    const float* aSrc = x + (size_t)(rowBase + sr) * 1080;
    f32x4 acc[4] = {};
    float4 c0, c1;
    auto LD = [&](int s, float4& d) {
      int gk = s * 64 + sc;
      d = (gk < 1080) ? *(const float4*)(aSrc + gk) : make_float4(0.f, 0.f, 0.f, 0.f);
    };
    LD(0, c0);
    LD(1, c1);
    for (int s = 0; s < 17; ++s) {
      bf16x4 w4;
      w4[0] = (__bf16)c0.x; w4[1] = (__bf16)c0.y;
      w4[2] = (__bf16)c0.z; w4[3] = (__bf16)c0.w;
      *reinterpret_cast<bf16x4*>(&Alds[sr][sc]) = w4;
      __syncthreads();
      c0 = c1;
      if (s + 2 < 17) LD(s + 2, c1);
      int arow = wr16 + (lane & 15);
#pragma unroll
      for (int ks = 0; ks < 2; ++ks) {
        int ak = ks * 32 + (lane >> 4) * 8;
        bf16x8 a0 = *reinterpret_cast<const bf16x8*>(&Alds[arow][ak]);
        int kt = s * 2 + ks;
#pragma unroll
        for (int n = 0; n < 4; ++n) {
          bf16x8 bv = ldB(W1p, kt, 16, wc4 + n, lane);
          acc[n] = mfma_bf16(a0, bv, acc[n]);
        }
      }
      __syncthreads();
    }
#pragma unroll
    for (int n = 0; n < 4; ++n) {
      int col = wc64 + n * 16 + (lane & 15);
      float bb = b1[col];
#pragma unroll
      for (int j = 0; j < 4; ++j) {
        int rl = wr16 + q4 + j;
        float h = acc[n][j] + bb;
        m1T[(size_t)col * 16384 + rowBase + rl] = (__bf16)(h > 0.f ? 1.f : 0.f);
        h1s[rl][col] = (__bf16)fmaxf(h, 0.f);
      }
    }
    __syncthreads();
    f32x4 acc2[4] = {};
#pragma unroll
    for (int ks = 0; ks < 8; ++ks) {
      int arow = wr16 + (lane & 15), ak = ks * 32 + (lane >> 4) * 8;
      bf16x8 a0 = *reinterpret_cast<const bf16x8*>(&h1s[arow][ak]);
#pragma unroll
      for (int n = 0; n < 4; ++n) {
        bf16x8 bv = ldB(W2p, ks, 16, wc4 + n, lane);
        acc2[n] = mfma_bf16(a0, bv, acc2[n]);
      }
    }
#pragma unroll
    for (int n = 0; n < 4; ++n) {
      int col = wc64 + n * 16 + (lane & 15);
      float bb = b2[col];
#pragma unroll
      for (int j = 0; j < 4; ++j) {
        int rl = wr16 + q4 + j;
        float h = acc2[n][j] + bb;
        m2T[(size_t)col * 16384 + rowBase + rl] = (__bf16)(h > 0.f ? 1.f : 0.f);
      }
    }
  }
  gridbar(cnt, 1024);

  // ---- P2: blocks 0..255 masks GEMM (streaming, atomicAdd-exact);
  //          blocks 256..511 g1 = relu(mc@Wg1^T+bg1) -> zgeo ----
  if (bid < 256) {
    int iz = bid & 31, ij = bid >> 5;
    int ibase = (ij >> 1) * 64, jbase = (ij & 1) * 128;
    int wr = wid >> 2, wc = wid & 3;
    size_t b0 = (size_t)iz * 512 + (lane >> 4) * 8;
    const __bf16* pa0 = m2T + (size_t)(ibase + wr * 32 + (lane & 15)) * 16384 + b0;
    const __bf16* pa1 = pa0 + (size_t)16 * 16384;
    const __bf16* pb0 = m1T + (size_t)(jbase + wc * 32 + (lane & 15)) * 16384 + b0;
    const __bf16* pb1 = pb0 + (size_t)16 * 16384;
    f32x4 acc[2][2] = {};
#pragma unroll 4
    for (int c = 0; c < 16; ++c) {
      bf16x8 a0 = *reinterpret_cast<const bf16x8*>(pa0 + c * 32);
      bf16x8 a1 = *reinterpret_cast<const bf16x8*>(pa1 + c * 32);
      bf16x8 bv0 = *reinterpret_cast<const bf16x8*>(pb0 + c * 32);
      bf16x8 bv1 = *reinterpret_cast<const bf16x8*>(pb1 + c * 32);
      acc[0][0] = mfma_bf16(a0, bv0, acc[0][0]);
      acc[0][1] = mfma_bf16(a0, bv1, acc[0][1]);
      acc[1][0] = mfma_bf16(a1, bv0, acc[1][0]);
      acc[1][1] = mfma_bf16(a1, bv1, acc[1][1]);
    }
#pragma unroll
    for (int m = 0; m < 2; ++m)
#pragma unroll
      for (int n = 0; n < 2; ++n)
#pragma unroll
        for (int j = 0; j < 4; ++j) {
          int gi = ibase + wr * 32 + m * 16 + q4 + j;
          int gj = jbase + wc * 32 + n * 16 + (lane & 15);
          atomicAdd(&G[(size_t)gi * 256 + gj], acc[m][n][j] * (1.f / 16384.f));
        }
  } else {
    __bf16 (*Alds2)[40] = (__bf16(*)[40])SM;
    __bf16 (*g1S)[264] = (__bf16(*)[264])(SM + 5120);
    int wr = wid >> 2, wc = wid & 3;
    int rowBase = (bid - 256) * 64;
    int sr = tid >> 3, sc = (tid & 7) * 4;
    const float* aSrc = mc + (size_t)(rowBase + sr) * 200;
    f32x4 acc[2][4] = {};
    for (int kt = 0; kt < 7; ++kt) {
      int gk = kt * 32 + sc;
      bf16x4 w4;
      if (gk < 200) {
        float4 v = *(const float4*)(aSrc + gk);
        w4[0] = (__bf16)v.x; w4[1] = (__bf16)v.y;
        w4[2] = (__bf16)v.z; w4[3] = (__bf16)v.w;
      } else {
        w4[0] = w4[1] = w4[2] = w4[3] = (__bf16)0.f;
      }
      *reinterpret_cast<bf16x4*>(&Alds2[sr][sc]) = w4;
      __syncthreads();
      int arow = wr * 32 + (lane & 15), ak = (lane >> 4) * 8;
      bf16x8 a0 = *reinterpret_cast<const bf16x8*>(&Alds2[arow][ak]);
      bf16x8 a1 = *reinterpret_cast<const bf16x8*>(&Alds2[arow + 16][ak]);
#pragma unroll
      for (int n = 0; n < 4; ++n) {
        bf16x8 bv = ldB(Wg1p, kt, 16, wc * 4 + n, lane);
        acc[0][n] = mfma_bf16(a0, bv, acc[0][n]);
        acc[1][n] = mfma_bf16(a1, bv, acc[1][n]);
      }
      __syncthreads();
    }
#pragma unroll
    for (int m = 0; m < 2; ++m)
#pragma unroll
      for (int n = 0; n < 4; ++n) {
        int col = wc * 64 + n * 16 + (lane & 15);
        float bb = bg1[col];
#pragma unroll
        for (int j = 0; j < 4; ++j) {
          int rl = wr * 32 + m * 16 + q4 + j;
          g1S[rl][col] = (__bf16)fmaxf(acc[m][n][j] + bb, 0.f);
        }
      }
    __syncthreads();
    f32x4 acc2[2][2] = {};
#pragma unroll
    for (int ks = 0; ks < 8; ++ks) {
      int arow = wr * 32 + (lane & 15), ak = ks * 32 + (lane >> 4) * 8;
      bf16x8 a0 = *reinterpret_cast<const bf16x8*>(&g1S[arow][ak]);
      bf16x8 a1 = *reinterpret_cast<const bf16x8*>(&g1S[arow + 16][ak]);
#pragma unroll
      for (int n = 0; n < 2; ++n) {
        bf16x8 bv = ldB(Wg2p, ks, 8, wc * 2 + n, lane);
        acc2[0][n] = mfma_bf16(a0, bv, acc2[0][n]);
        acc2[1][n] = mfma_bf16(a1, bv, acc2[1][n]);
      }
    }
#pragma unroll
    for (int m = 0; m < 2; ++m)
#pragma unroll
      for (int n = 0; n < 2; ++n) {
        int col = wc * 32 + n * 16 + (lane & 15);
        float bb = bg2[col];
#pragma unroll
        for (int j = 0; j < 4; ++j) {
          int row = rowBase + wr * 32 + m * 16 + q4 + j;
          o_zgeo[(size_t)row * 128 + col] = acc2[m][n][j] + bb;
        }
      }
  }
  gridbar(cnt, 1536);

  // ---- P3a: T = (W2 .* G) @ W1[:, -360:]  (24 tiles) ----
  if (bid < 24)
    small_body(SM, tid, W2, G, 256, W1 + 720, 1080, T, 384,
               256, 360, 256, (bid / 6) * 64, (bid % 6) * 64);
  gridbar(cnt, 2048);

  // ---- P3b: ec = W3 @ T  (36 tiles) ----
  if (bid < 36)
    small_body(SM, tid, W3, nullptr, 256, T, 384, o_ec, 360,
               360, 360, 256, (bid / 6) * 64, (bid % 6) * 64);
}

// ---------------------------------------------------------------------------
// mega2: P4 gemv_p (512 rows) | bar | P5 tail (znpi1 per block + zsum/norm +
// r1 + recon), 512 tiles of 32 rows.
// ---------------------------------------------------------------------------
__global__ __launch_bounds__(512, 4) void mega2(
    const float* __restrict__ Wp1, const float* __restrict__ ec,
    const float* __restrict__ bp1, float* __restrict__ p,
    const float* __restrict__ Wp2, const float* __restrict__ bp2,
    const float* __restrict__ zgeo,
    const __bf16* __restrict__ Wr1p, const float* __restrict__ br1,
    const __bf16* __restrict__ Wr2p, const float* __restrict__ br2,
    float* __restrict__ o_znpi, float* __restrict__ o_zn,
    float* __restrict__ o_rec, int* __restrict__ cnt) {
  __shared__ __align__(16) char SM[28160];
  int tid = threadIdx.x, bid = blockIdx.x;
  int lane = tid & 63, wid = tid >> 6;
  int q4 = (lane >> 4) * 4;

  // ---- P4: p[bid] = relu(Wp1[bid,:] . ec + bp1[bid]) ----
  {
    float* redw = (float*)SM;
    const float4* w = (const float4*)(Wp1 + (size_t)bid * 129600);
    const float4* e = (const float4*)ec;
    float s = 0.f;
    for (int i = tid; i < 32400; i += 512) {
      float4 a = w[i], b = e[i];
      s += a.x * b.x + a.y * b.y + a.z * b.z + a.w * b.w;
    }
    for (int o = 32; o; o >>= 1) s += __shfl_down(s, o);
    if (lane == 0) redw[wid] = s;
    __syncthreads();
    if (tid == 0) {
      float tot = 0.f;
#pragma unroll
      for (int i = 0; i < 8; ++i) tot += redw[i];
      p[bid] = fmaxf(tot + bp1[bid], 0.f);
    }
  }
  gridbar(cnt, 512);

  // ---- P5: tail on 32-row tile ----
  {
    float* pS = (float*)SM;                          // 512 f32
    float* znpiS = (float*)(SM + 2048);              // 128 f32
    __bf16 (*znS)[136] = (__bf16(*)[136])(SM + 2560);
    __bf16 (*r1S)[264] = (__bf16(*)[264])(SM + 11264);
    int rowBase = bid * 32;
    pS[tid] = p[tid];
    __syncthreads();
    {  // znpi1 per block: col = tid>>2, 4-thread K-split
      int col = tid >> 2, q = tid & 3;
      const float4* w = (const float4*)(Wp2 + (size_t)col * 512 + q * 128);
      const float4* pv = (const float4*)(pS + q * 128);
      float s = 0.f;
#pragma unroll
      for (int i = 0; i < 32; ++i) {
        float4 a = w[i], b = pv[i];
        s += a.x * b.x + a.y * b.y + a.z * b.z + a.w * b.w;
      }
      s += __shfl_xor(s, 1);
      s += __shfl_xor(s, 2);
      if (q == 0) znpiS[col] = s + bp2[col];
    }
    __syncthreads();
    {  // zsum + norm: 32 lanes per row
      int rg = tid >> 5, c4 = (tid & 31) * 4;
      float4 zp = make_float4(znpiS[c4], znpiS[c4 + 1], znpiS[c4 + 2], znpiS[c4 + 3]);
#pragma unroll
      for (int ri = 0; ri < 2; ++ri) {
        int rl = rg + ri * 16;
        int row = rowBase + rl;
        float4 zg = *(const float4*)(zgeo + (size_t)row * 128 + c4);
        float4 zs = make_float4(zg.x + zp.x, zg.y + zp.y, zg.z + zp.z, zg.w + zp.w);
        *(float4*)(o_znpi + (size_t)row * 128 + c4) = zp;
        float ss = zs.x * zs.x + zs.y * zs.y + zs.z * zs.z + zs.w * zs.w;
        ss += __shfl_xor(ss, 1);
        ss += __shfl_xor(ss, 2);
        ss += __shfl_xor(ss, 4);
        ss += __shfl_xor(ss, 8);
        ss += __shfl_xor(ss, 16);
        float rn = 1.f / fmaxf(sqrtf(ss), 1e-12f);
        float4 zn = make_float4(zs.x * rn, zs.y * rn, zs.z * rn, zs.w * rn);
        *(float4*)(o_zn + (size_t)row * 128 + c4) = zn;
        bf16x4 znb;
        znb[0] = (__bf16)zn.x; znb[1] = (__bf16)zn.y;
        znb[2] = (__bf16)zn.z; znb[3] = (__bf16)zn.w;
        *reinterpret_cast<bf16x4*>(&znS[rl][c4]) = znb;
      }
    }
    __syncthreads();
    int wr16 = (wid >> 2) * 16, wc = wid & 3;
    {  // r1 = relu(zn @ Wr1^T + br1)
      f32x4 acc[4] = {};
#pragma unroll
      for (int ks = 0; ks < 4; ++ks) {
        int arow = wr16 + (lane & 15), ak = ks * 32 + (lane >> 4) * 8;
        bf16x8 a0 = *reinterpret_cast<const bf16x8*>(&znS[arow][ak]);
#pragma unroll
        for (int n = 0; n < 4; ++n) {
          bf16x8 bv = ldB(Wr1p, ks, 16, wc * 4 + n, lane);
          acc[n] = mfma_bf16(a0, bv, acc[n]);
        }
      }
#pragma unroll
      for (int n = 0; n < 4; ++n) {
        int col = wc * 64 + n * 16 + (lane & 15);
        float bb = br1[col];
#pragma unroll
        for (int j = 0; j < 4; ++j)
          r1S[wr16 + q4 + j][col] = (__bf16)fmaxf(acc[n][j] + bb, 0.f);
      }
    }
    __syncthreads();
    {  // recon = r1 @ Wr2^T + br2 (N padded 384, store cols < 360)
      f32x4 acc[6] = {};
#pragma unroll
      for (int ks = 0; ks < 8; ++ks) {
        int arow = wr16 + (lane & 15), ak = ks * 32 + (lane >> 4) * 8;
        bf16x8 a0 = *reinterpret_cast<const bf16x8*>(&r1S[arow][ak]);
#pragma unroll
        for (int n = 0; n < 6; ++n) {
          bf16x8 bv = ldB(Wr2p, ks, 24, wc * 6 + n, lane);
          acc[n] = mfma_bf16(a0, bv, acc[n]);
        }
      }
#pragma unroll
      for (int n = 0; n < 6; ++n) {
        int col = wc * 96 + n * 16 + (lane & 15);
        if (col < 360) {
          float bb = br2[col];
#pragma unroll
          for (int j = 0; j < 4; ++j) {
            int rl = wr16 + q4 + j;
            o_rec[(size_t)(rowBase + rl) * 360 + col] = acc[n][j] + bb;
          }
        }
      }
    }
  }
}

// ---------------------------------------------------------------------------
extern "C" void kernel_launch(void* const* d_in, const int* in_sizes, int n_in,
                              void* d_out, int out_size, void* d_ws,
                              size_t ws_size, hipStream_t stream) {
  (void)in_sizes; (void)n_in; (void)out_size; (void)ws_size;
  const float* x   = (const float*)d_in[0];
  const float* mc  = (const float*)d_in[2];
  const float* W1  = (const float*)d_in[3];  const float* b1  = (const float*)d_in[4];
  const float* W2  = (const float*)d_in[5];  const float* b2  = (const float*)d_in[6];
  const float* W3  = (const float*)d_in[7];
  const float* Wp1 = (const float*)d_in[9];  const float* bp1 = (const float*)d_in[10];
  const float* Wp2 = (const float*)d_in[11]; const float* bp2 = (const float*)d_in[12];
  const float* Wg1 = (const float*)d_in[13]; const float* bg1 = (const float*)d_in[14];
  const float* Wg2 = (const float*)d_in[15]; const float* bg2 = (const float*)d_in[16];
  const float* Wr1 = (const float*)d_in[17]; const float* br1 = (const float*)d_in[18];
  const float* Wr2 = (const float*)d_in[19]; const float* br2 = (const float*)d_in[20];

  float* out = (float*)d_out;
  float* o_znpi = out;                  // (B,128)
  float* o_zgeo = out + 2097152;        // (B,128)
  float* o_zn   = out + 4194304;        // (B,128)
  float* o_ec   = out + 6291456;        // (360,360)
  float* o_rec  = out + 6421056;        // (B,360)

  char* ws = (char*)d_ws;
  __bf16* m1T   = (__bf16*)(ws + 0);            // (256,16384)
  __bf16* m2T   = (__bf16*)(ws + 8388608);      // (256,16384)
  float*  G     = (float*)(ws + 16777216);      // 256x256
  float*  T     = (float*)(ws + 17039360);      // 256x384
  float*  p512  = (float*)(ws + 17432576);      // 512
  __bf16* W1p   = (__bf16*)(ws + 17434624);
  __bf16* W2p   = W1p  + (size_t)544 * 512;
  __bf16* Wg1p  = W2p  + (size_t)128 * 512;
  __bf16* Wg2p  = Wg1p + (size_t)112 * 512;
  __bf16* Wr1p  = Wg2p + (size_t)64 * 512;
  __bf16* Wr2p  = Wr1p + (size_t)64 * 512;
  int*    cnt   = (int*)(ws + 18565120);        // [0]=mega1, [1]=mega2

  hipMemsetAsync(cnt, 0, 64, stream);
  mega1<<<512, 512, 0, stream>>>(x, W1, b1, W2, b2, W3, mc, Wg1, bg1, Wg2, bg2,
                                 Wr1, Wr2, W1p, W2p, Wg1p, Wg2p, Wr1p, Wr2p,
                                 m1T, m2T, G, T, o_zgeo, o_ec, cnt);
  mega2<<<512, 512, 0, stream>>>(Wp1, o_ec, bp1, p512, Wp2, bp2, o_zgeo,
                                 Wr1p, br1, Wr2p, br2, o_znpi, o_zn, o_rec,
                                 cnt + 1);
}

// Round 5
// 261.234 us; speedup vs baseline: 2.0930x; 2.0930x over previous
//
#include <hip/hip_runtime.h>

typedef __bf16 bf16x8 __attribute__((ext_vector_type(8)));
typedef __bf16 bf16x4 __attribute__((ext_vector_type(4)));
typedef float  f32x4  __attribute__((ext_vector_type(4)));

__device__ __forceinline__ f32x4 mfma_bf16(bf16x8 a, bf16x8 b, f32x4 c) {
  return __builtin_amdgcn_mfma_f32_16x16x32_bf16(a, b, c, 0, 0, 0);
}
// Packed B-fragment load: Bp[((kt*NT+nt)*64+lane)*8 .. +7]
__device__ __forceinline__ bf16x8 ldB(const __bf16* Bp, int kt, int NT, int nt,
                                      int lane) {
  return *reinterpret_cast<const bf16x8*>(Bp + (((size_t)kt * NT + nt) * 64 + lane) * 8);
}

// Grid barrier -- ONLY for tiny grids (<= ~40 blocks). R4 lesson: full-grid
// spin barriers (512 blocks) cost ~100s of microseconds (L2-invalidate per
// acquire + counter-line contention). At 36 blocks the spin is negligible.
__device__ __forceinline__ void gridbar(int* cnt, int target) {
  __syncthreads();
  if (threadIdx.x == 0) {
    __threadfence();
    __hip_atomic_fetch_add(cnt, 1, __ATOMIC_RELEASE, __HIP_MEMORY_SCOPE_AGENT);
    while (__hip_atomic_load(cnt, __ATOMIC_RELAXED, __HIP_MEMORY_SCOPE_AGENT) < target)
      __builtin_amdgcn_s_sleep(4);
    __threadfence();
  }
  __syncthreads();
}

// ---------------------------------------------------------------------------
// All weight packs in ONE kernel + zero G + zero gridbar counter.
// pack: out[((kt*NT+nt)*64+lane)*8+e] = W[nt*16+(lane&15)][kt*32+(lane>>4)*8+e]
// ---------------------------------------------------------------------------
__global__ void pack_all(const float* __restrict__ W1, const float* __restrict__ W2,
                         const float* __restrict__ Wg1, const float* __restrict__ Wg2,
                         const float* __restrict__ Wr1, const float* __restrict__ Wr2,
                         __bf16* __restrict__ W1p, __bf16* __restrict__ W2p,
                         __bf16* __restrict__ Wg1p, __bf16* __restrict__ Wg2p,
                         __bf16* __restrict__ Wr1p, __bf16* __restrict__ Wr2p,
                         float* __restrict__ G, int* __restrict__ cnt) {
  int bx = blockIdx.x;
  int lane = threadIdx.x;
  if (bx >= 1104) {  // zero G (256x256 f32): 32 blocks x 64 thr x 8 float4
    if (bx == 1104 && lane == 0) cnt[0] = 0;  // small_pair barrier counter
    float4* g = (float4*)G;
    int base = (bx - 1104) * 512 + lane;
#pragma unroll
    for (int i = 0; i < 8; ++i) g[base + i * 64] = make_float4(0.f, 0.f, 0.f, 0.f);
    return;
  }
  const float* W; __bf16* out; int N, K, NT, local;
  if (bx < 544)      { W = W1;  out = W1p;  N = 256; K = 1080; NT = 16; local = bx; }
  else if (bx < 672) { W = W2;  out = W2p;  N = 256; K = 256;  NT = 16; local = bx - 544; }
  else if (bx < 784) { W = Wg1; out = Wg1p; N = 256; K = 200;  NT = 16; local = bx - 672; }
  else if (bx < 848) { W = Wg2; out = Wg2p; N = 128; K = 256;  NT = 8;  local = bx - 784; }
  else if (bx < 912) { W = Wr1; out = Wr1p; N = 256; K = 128;  NT = 16; local = bx - 848; }
  else               { W = Wr2; out = Wr2p; N = 360; K = 256;  NT = 24; local = bx - 912; }
  int nt = local % NT, kt = local / NT;
  int n = nt * 16 + (lane & 15);
  int k0 = kt * 32 + (lane >> 4) * 8;
  bf16x8 v;
#pragma unroll
  for (int e = 0; e < 8; ++e) {
    int k = k0 + e;
    float xv = (n < N && k < K) ? W[(size_t)n * K + k] : 0.f;
    v[e] = (__bf16)xv;
  }
  *reinterpret_cast<bf16x8*>(out + ((size_t)local * 64 + lane) * 8) = v;
}

// ---------------------------------------------------------------------------
// Fused surrogate: h1 = x@W1^T+b1 (K=1080, K_STEP=64 -> 17 barrier pairs),
// masks written TRANSPOSED: mT[col][row], col-major for streaming masks GEMM.
// relu(h1) stays in LDS; h2 = relu(h1)@W2^T+b2. Tile 32x256, 4 waves, grid 512.
// ---------------------------------------------------------------------------
__global__ __launch_bounds__(256) void h1h2_fused(
    const float* __restrict__ x, const __bf16* __restrict__ W1p,
    const float* __restrict__ b1, const __bf16* __restrict__ W2p,
    const float* __restrict__ b2, __bf16* __restrict__ m1T,
    __bf16* __restrict__ m2T) {
  __shared__ __bf16 Alds[32][68];    // 64-wide K-slab, stride 68 (~2-way banks)
  __shared__ __bf16 h1s[32][264];    // relu(h1)
  int tid = threadIdx.x;
  int lane = tid & 63, wid = tid >> 6;
  int rowBase = blockIdx.x * 32;
  int sr = tid >> 3, sc = (tid & 7) * 8;
  const float* aSrc = x + (size_t)(rowBase + sr) * 1080;
  f32x4 acc[2][4] = {};
  float4 c0a, c0b, c1a, c1b;
  auto LD = [&](int s, float4& a, float4& b) {
    int gk = s * 64 + sc;
    if (gk < 1080) {
      a = *(const float4*)(aSrc + gk);
      b = *(const float4*)(aSrc + gk + 4);
    } else {
      a = make_float4(0.f, 0.f, 0.f, 0.f);
      b = a;
    }
  };
  LD(0, c0a, c0b);
  LD(1, c1a, c1b);
  for (int s = 0; s < 17; ++s) {
    bf16x8 w8;
    w8[0] = (__bf16)c0a.x; w8[1] = (__bf16)c0a.y; w8[2] = (__bf16)c0a.z; w8[3] = (__bf16)c0a.w;
    w8[4] = (__bf16)c0b.x; w8[5] = (__bf16)c0b.y; w8[6] = (__bf16)c0b.z; w8[7] = (__bf16)c0b.w;
    *reinterpret_cast<bf16x8*>(&Alds[sr][sc]) = w8;
    __syncthreads();
    c0a = c1a; c0b = c1b;
    if (s + 2 < 17) LD(s + 2, c1a, c1b);
    int arow = lane & 15;
#pragma unroll
    for (int ks = 0; ks < 2; ++ks) {
      int ak = ks * 32 + (lane >> 4) * 8;
      bf16x8 a0 = *reinterpret_cast<const bf16x8*>(&Alds[arow][ak]);
      bf16x8 a1 = *reinterpret_cast<const bf16x8*>(&Alds[arow + 16][ak]);
      int kt = s * 2 + ks;
#pragma unroll
      for (int n = 0; n < 4; ++n) {
        bf16x8 bv = ldB(W1p, kt, 16, wid * 4 + n, lane);
        acc[0][n] = mfma_bf16(a0, bv, acc[0][n]);
        acc[1][n] = mfma_bf16(a1, bv, acc[1][n]);
      }
    }
    __syncthreads();
  }
  int q4 = (lane >> 4) * 4;
#pragma unroll
  for (int m = 0; m < 2; ++m)
#pragma unroll
    for (int n = 0; n < 4; ++n) {
      int col = wid * 64 + n * 16 + (lane & 15);
      float bb = b1[col];
#pragma unroll
      for (int j = 0; j < 4; ++j) {
        int rl = m * 16 + q4 + j;
        float h = acc[m][n][j] + bb;
        m1T[(size_t)col * 16384 + rowBase + rl] = (__bf16)(h > 0.f ? 1.f : 0.f);
        h1s[rl][col] = (__bf16)fmaxf(h, 0.f);
      }
    }
  __syncthreads();
  // ---- h2 phase: K=256 from LDS ----
  f32x4 acc2[2][4] = {};
#pragma unroll
  for (int ks = 0; ks < 8; ++ks) {
    int arow = lane & 15, ak = ks * 32 + (lane >> 4) * 8;
    bf16x8 a0 = *reinterpret_cast<const bf16x8*>(&h1s[arow][ak]);
    bf16x8 a1 = *reinterpret_cast<const bf16x8*>(&h1s[arow + 16][ak]);
#pragma unroll
    for (int n = 0; n < 4; ++n) {
      bf16x8 bv = ldB(W2p, ks, 16, wid * 4 + n, lane);
      acc2[0][n] = mfma_bf16(a0, bv, acc2[0][n]);
      acc2[1][n] = mfma_bf16(a1, bv, acc2[1][n]);
    }
  }
#pragma unroll
  for (int m = 0; m < 2; ++m)
#pragma unroll
    for (int n = 0; n < 4; ++n) {
      int col = wid * 64 + n * 16 + (lane & 15);
      float bb = b2[col];
#pragma unroll
      for (int j = 0; j < 4; ++j) {
        int rl = m * 16 + q4 + j;
        float h = acc2[m][n][j] + bb;
        m2T[(size_t)col * 16384 + rowBase + rl] = (__bf16)(h > 0.f ? 1.f : 0.f);
      }
    }
}

// ---------------------------------------------------------------------------
// Streaming masks GEMM: G += (1/B) * m2[chunk]^T @ m1[chunk].
// Transposed mask layout -> A/B fragments are direct contiguous bf16x8 loads.
// No LDS, no barriers. Partial tiles are exact dyadic rationals -> atomicAdd
// into G is exact & deterministic.
// ---------------------------------------------------------------------------
__global__ __launch_bounds__(256) void gemm_masks(
    const __bf16* __restrict__ m2T, const __bf16* __restrict__ m1T,
    float* __restrict__ G) {
  int tid = threadIdx.x;
  int lane = tid & 63, wid = tid >> 6;
  int wr = wid >> 1, wc = wid & 1;
  int ibase = blockIdx.x * 64, jbase = blockIdx.y * 64;
  size_t b0 = (size_t)blockIdx.z * 1024 + (lane >> 4) * 8;
  const __bf16* pa0 = m2T + (size_t)(ibase + wr * 32 + (lane & 15)) * 16384 + b0;
  const __bf16* pa1 = pa0 + (size_t)16 * 16384;
  const __bf16* pb0 = m1T + (size_t)(jbase + wc * 32 + (lane & 15)) * 16384 + b0;
  const __bf16* pb1 = pb0 + (size_t)16 * 16384;
  f32x4 acc[2][2] = {};
#pragma unroll 4
  for (int c = 0; c < 32; ++c) {
    bf16x8 a0 = *reinterpret_cast<const bf16x8*>(pa0 + c * 32);
    bf16x8 a1 = *reinterpret_cast<const bf16x8*>(pa1 + c * 32);
    bf16x8 bv0 = *reinterpret_cast<const bf16x8*>(pb0 + c * 32);
    bf16x8 bv1 = *reinterpret_cast<const bf16x8*>(pb1 + c * 32);
    acc[0][0] = mfma_bf16(a0, bv0, acc[0][0]);
    acc[0][1] = mfma_bf16(a0, bv1, acc[0][1]);
    acc[1][0] = mfma_bf16(a1, bv0, acc[1][0]);
    acc[1][1] = mfma_bf16(a1, bv1, acc[1][1]);
  }
  int q4 = (lane >> 4) * 4;
#pragma unroll
  for (int m = 0; m < 2; ++m)
#pragma unroll
    for (int n = 0; n < 2; ++n)
#pragma unroll
      for (int j = 0; j < 4; ++j) {
        int gi = ibase + wr * 32 + m * 16 + q4 + j;
        int gj = jbase + wc * 32 + n * 16 + (lane & 15);
        atomicAdd(&G[(size_t)gi * 256 + gj], acc[m][n][j] * (1.f / 16384.f));
      }
}

// ---------------------------------------------------------------------------
// 64x64-tile f32 GEMM body (256 threads): C[MxN] = (A .* A2) @ B
// ---------------------------------------------------------------------------
__device__ void small_body(float (*As)[17], float (*Bs)[65], int t,
                           const float* __restrict__ A, const float* __restrict__ A2,
                           int lda, const float* __restrict__ Bm, int ldb,
                           float* __restrict__ C, int ldc,
                           int M, int N, int K, int m0, int n0) {
  int tx = t & 15, ty = t >> 4;
  float acc[4][4] = {};
  for (int k0 = 0; k0 < K; k0 += 16) {
#pragma unroll
    for (int i = 0; i < 4; ++i) {
      int idx = t * 4 + i;
      int r = idx >> 4, kk = idx & 15;
      int gm = m0 + r, gk = k0 + kk;
      float v = (gm < M && gk < K) ? A[(size_t)gm * lda + gk] : 0.f;
      if (A2 && gm < M && gk < K) v *= A2[(size_t)gm * lda + gk];
      As[r][kk] = v;
      int kk2 = idx >> 6, cc = idx & 63;
      int gk2 = k0 + kk2, gn = n0 + cc;
      Bs[kk2][cc] = (gk2 < K && gn < N) ? Bm[(size_t)gk2 * ldb + gn] : 0.f;
    }
    __syncthreads();
#pragma unroll
    for (int kk = 0; kk < 16; ++kk)
#pragma unroll
      for (int i = 0; i < 4; ++i)
#pragma unroll
        for (int j = 0; j < 4; ++j)
          acc[i][j] += As[ty * 4 + i][kk] * Bs[kk][tx * 4 + j];
    __syncthreads();
  }
#pragma unroll
  for (int i = 0; i < 4; ++i)
#pragma unroll
    for (int j = 0; j < 4; ++j) {
      int gm = m0 + ty * 4 + i, gn = n0 + tx * 4 + j;
      if (gm < M && gn < N) C[(size_t)gm * ldc + gn] = acc[i][j];
    }
}

// ---------------------------------------------------------------------------
// small_pair: T = (W2 .* G) @ W1[:, -360:]  (24 tiles)  | gridbar(36) |
//             ec = W3 @ T                   (36 tiles)
// 36 blocks -> trivially co-resident; tiny spin. cnt zeroed by pack_all.
// ---------------------------------------------------------------------------
__global__ __launch_bounds__(256) void small_pair(
    const float* __restrict__ W2, const float* __restrict__ G,
    const float* __restrict__ W1, const float* __restrict__ W3,
    float* __restrict__ T, float* __restrict__ o_ec, int* __restrict__ cnt) {
  __shared__ float As[64][17];
  __shared__ float Bs[16][65];
  int t = threadIdx.x, bid = blockIdx.x;
  if (bid < 24)
    small_body(As, Bs, t, W2, G, 256, W1 + 720, 1080, T, 384,
               256, 360, 256, (bid / 6) * 64, (bid % 6) * 64);
  gridbar(cnt, 36);
  small_body(As, Bs, t, W3, nullptr, 256, T, 384, o_ec, 360,
             360, 360, 256, (bid / 6) * 64, (bid % 6) * 64);
}

// ---------------------------------------------------------------------------
// Fused: blocks 0..511 -> gemv_p (HBM-bound Wp1 read);
//        blocks 512..767 -> g1 = relu(mc@Wg1^T+bg1) in LDS, then
//                           o_zgeo = g1@Wg2^T+bg2 (rides free under Wp1 stream).
// ---------------------------------------------------------------------------
__global__ __launch_bounds__(512) void p_and_g1(
    const float* __restrict__ Wp1, const float* __restrict__ ec,
    const float* __restrict__ bp1, float* __restrict__ p,
    const float* __restrict__ mc, const __bf16* __restrict__ Wg1p,
    const float* __restrict__ bg1, const __bf16* __restrict__ Wg2p,
    const float* __restrict__ bg2, float* __restrict__ o_zgeo) {
  __shared__ __bf16 Alds[64][40];
  __shared__ __bf16 g1S[64][264];
  __shared__ float redw[8];
  int t = threadIdx.x;
  if (blockIdx.x < 512) {
    int row = blockIdx.x;
    const float4* w = (const float4*)(Wp1 + (size_t)row * 129600);
    const float4* e = (const float4*)ec;
    float s = 0.f;
    for (int i = t; i < 32400; i += 512) {
      float4 a = w[i], b = e[i];
      s += a.x * b.x + a.y * b.y + a.z * b.z + a.w * b.w;
    }
    for (int o = 32; o; o >>= 1) s += __shfl_down(s, o);
    if ((t & 63) == 0) redw[t >> 6] = s;
    __syncthreads();
    if (t == 0) {
      float tot = 0.f;
#pragma unroll
      for (int i = 0; i < 8; ++i) tot += redw[i];
      p[row] = fmaxf(tot + bp1[row], 0.f);
    }
  } else {
    int lane = t & 63, wid = t >> 6;
    int wr = wid >> 2, wc = wid & 3;
    int rowBase = (blockIdx.x - 512) * 64;
    int sr = t >> 3, sc = (t & 7) * 4;
    const float* aSrc = mc + (size_t)(rowBase + sr) * 200;
    int q4 = (lane >> 4) * 4;
    f32x4 acc[2][4] = {};
    for (int kt = 0; kt < 7; ++kt) {
      int gk = kt * 32 + sc;
      bf16x4 w4;
      if (gk < 200) {
        float4 v = *(const float4*)(aSrc + gk);
        w4[0] = (__bf16)v.x; w4[1] = (__bf16)v.y;
        w4[2] = (__bf16)v.z; w4[3] = (__bf16)v.w;
      } else {
        w4[0] = w4[1] = w4[2] = w4[3] = (__bf16)0.f;
      }
      *reinterpret_cast<bf16x4*>(&Alds[sr][sc]) = w4;
      __syncthreads();
      int arow = wr * 32 + (lane & 15), ak = (lane >> 4) * 8;
      bf16x8 a0 = *reinterpret_cast<const bf16x8*>(&Alds[arow][ak]);
      bf16x8 a1 = *reinterpret_cast<const bf16x8*>(&Alds[arow + 16][ak]);
#pragma unroll
      for (int n = 0; n < 4; ++n) {
        bf16x8 bv = ldB(Wg1p, kt, 16, wc * 4 + n, lane);
        acc[0][n] = mfma_bf16(a0, bv, acc[0][n]);
        acc[1][n] = mfma_bf16(a1, bv, acc[1][n]);
      }
      __syncthreads();
    }
#pragma unroll
    for (int m = 0; m < 2; ++m)
#pragma unroll
      for (int n = 0; n < 4; ++n) {
        int col = wc * 64 + n * 16 + (lane & 15);
        float bb = bg1[col];
#pragma unroll
        for (int j = 0; j < 4; ++j) {
          int rl = wr * 32 + m * 16 + q4 + j;
          g1S[rl][col] = (__bf16)fmaxf(acc[m][n][j] + bb, 0.f);
        }
      }
    __syncthreads();
    // ---- zgeo = g1 @ Wg2^T + bg2 (N=128) ----
    f32x4 acc2[2][2] = {};
#pragma unroll
    for (int ks = 0; ks < 8; ++ks) {
      int arow = wr * 32 + (lane & 15), ak = ks * 32 + (lane >> 4) * 8;
      bf16x8 a0 = *reinterpret_cast<const bf16x8*>(&g1S[arow][ak]);
      bf16x8 a1 = *reinterpret_cast<const bf16x8*>(&g1S[arow + 16][ak]);
#pragma unroll
      for (int n = 0; n < 2; ++n) {
        bf16x8 bv = ldB(Wg2p, ks, 8, wc * 2 + n, lane);
        acc2[0][n] = mfma_bf16(a0, bv, acc2[0][n]);
        acc2[1][n] = mfma_bf16(a1, bv, acc2[1][n]);
      }
    }
#pragma unroll
    for (int m = 0; m < 2; ++m)
#pragma unroll
      for (int n = 0; n < 2; ++n) {
        int col = wc * 32 + n * 16 + (lane & 15);
        float bb = bg2[col];
#pragma unroll
        for (int j = 0; j < 4; ++j) {
          int row = rowBase + wr * 32 + m * 16 + q4 + j;
          o_zgeo[(size_t)row * 128 + col] = acc2[m][n][j] + bb;
        }
      }
  }
}

// ---------------------------------------------------------------------------
// Tail: znpi1 recomputed per block (Wp2 is L3-resident); zsum = zgeo + znpi1;
// zn = normalize(zsum); r1 = relu(zn@Wr1^T+br1); recon = r1@Wr2^T+br2.
// One block = 64 rows, 8 waves. zn, r1 live in LDS.
// ---------------------------------------------------------------------------
__global__ __launch_bounds__(512) void mega_tail(
    const float* __restrict__ p, const float* __restrict__ Wp2,
    const float* __restrict__ bp2, const float* __restrict__ zgeo,
    const __bf16* __restrict__ Wr1p, const float* __restrict__ br1,
    const __bf16* __restrict__ Wr2p, const float* __restrict__ br2,
    float* __restrict__ o_znpi, float* __restrict__ o_zn,
    float* __restrict__ o_rec) {
  __shared__ __bf16 r1S[64][264];
  __shared__ __bf16 znS[64][136];
  __shared__ float znpiS[128];
  __shared__ float pS[512];
  int tid = threadIdx.x;
  int lane = tid & 63, wid = tid >> 6;
  int wr = wid >> 2, wc = wid & 3;
  int rowBase = blockIdx.x * 64;
  int q4 = (lane >> 4) * 4;
  pS[tid] = p[tid];
  __syncthreads();
  {  // znpi1 per block: col = tid>>2, 4-thread K-split (validated in R4 mega2)
    int col = tid >> 2, q = tid & 3;
    const float4* w = (const float4*)(Wp2 + (size_t)col * 512 + q * 128);
    const float4* pv = (const float4*)(pS + q * 128);
    float s = 0.f;
#pragma unroll
    for (int i = 0; i < 32; ++i) {
      float4 a = w[i], b = pv[i];
      s += a.x * b.x + a.y * b.y + a.z * b.z + a.w * b.w;
    }
    s += __shfl_xor(s, 1);
    s += __shfl_xor(s, 2);
    if (q == 0) znpiS[col] = s + bp2[col];
  }
  __syncthreads();
  // ---- phase A: zsum + norm (thread group of 32 owns one row) ----
  {
    int rg = tid >> 5;          // 0..15
    int c4 = (tid & 31) * 4;    // 0..124
    float4 zp = make_float4(znpiS[c4], znpiS[c4 + 1], znpiS[c4 + 2], znpiS[c4 + 3]);
#pragma unroll
    for (int ri = 0; ri < 4; ++ri) {
      int rl = rg + ri * 16;
      int row = rowBase + rl;
      float4 zg = *(const float4*)(zgeo + (size_t)row * 128 + c4);
      float4 zs = make_float4(zg.x + zp.x, zg.y + zp.y, zg.z + zp.z, zg.w + zp.w);
      *(float4*)(o_znpi + (size_t)row * 128 + c4) = zp;
      float ss = zs.x * zs.x + zs.y * zs.y + zs.z * zs.z + zs.w * zs.w;
      ss += __shfl_xor(ss, 1);
      ss += __shfl_xor(ss, 2);
      ss += __shfl_xor(ss, 4);
      ss += __shfl_xor(ss, 8);
      ss += __shfl_xor(ss, 16);
      float rn = 1.f / fmaxf(sqrtf(ss), 1e-12f);
      float4 zn = make_float4(zs.x * rn, zs.y * rn, zs.z * rn, zs.w * rn);
      *(float4*)(o_zn + (size_t)row * 128 + c4) = zn;
      bf16x4 znb;
      znb[0] = (__bf16)zn.x; znb[1] = (__bf16)zn.y;
      znb[2] = (__bf16)zn.z; znb[3] = (__bf16)zn.w;
      *reinterpret_cast<bf16x4*>(&znS[rl][c4]) = znb;
    }
  }
  __syncthreads();
  // ---- phase B: r1 = relu(zn@Wr1^T+br1) -> r1S ----
  {
    f32x4 acc[2][4] = {};
#pragma unroll
    for (int ks = 0; ks < 4; ++ks) {
      int arow = wr * 32 + (lane & 15), ak = ks * 32 + (lane >> 4) * 8;
      bf16x8 a0 = *reinterpret_cast<const bf16x8*>(&znS[arow][ak]);
      bf16x8 a1 = *reinterpret_cast<const bf16x8*>(&znS[arow + 16][ak]);
#pragma unroll
      for (int n = 0; n < 4; ++n) {
        bf16x8 bv = ldB(Wr1p, ks, 16, wc * 4 + n, lane);
        acc[0][n] = mfma_bf16(a0, bv, acc[0][n]);
        acc[1][n] = mfma_bf16(a1, bv, acc[1][n]);
      }
    }
#pragma unroll
    for (int m = 0; m < 2; ++m)
#pragma unroll
      for (int n = 0; n < 4; ++n) {
        int col = wc * 64 + n * 16 + (lane & 15);
        float bb = br1[col];
#pragma unroll
        for (int j = 0; j < 4; ++j) {
          int rl = wr * 32 + m * 16 + q4 + j;
          r1S[rl][col] = (__bf16)fmaxf(acc[m][n][j] + bb, 0.f);
        }
      }
  }
  __syncthreads();
  // ---- phase C: recon = r1@Wr2^T+br2 (N=384 padded, store cols<360) ----
  {
    f32x4 acc[2][6] = {};
#pragma unroll
    for (int ks = 0; ks < 8; ++ks) {
      int arow = wr * 32 + (lane & 15), ak = ks * 32 + (lane >> 4) * 8;
      bf16x8 a0 = *reinterpret_cast<const bf16x8*>(&r1S[arow][ak]);
      bf16x8 a1 = *reinterpret_cast<const bf16x8*>(&r1S[arow + 16][ak]);
#pragma unroll
      for (int n = 0; n < 6; ++n) {
        bf16x8 bv = ldB(Wr2p, ks, 24, wc * 6 + n, lane);
        acc[0][n] = mfma_bf16(a0, bv, acc[0][n]);
        acc[1][n] = mfma_bf16(a1, bv, acc[1][n]);
      }
    }
#pragma unroll
    for (int m = 0; m < 2; ++m)
#pragma unroll
      for (int n = 0; n < 6; ++n) {
        int col = wc * 96 + n * 16 + (lane & 15);
        if (col < 360) {
          float bb = br2[col];
#pragma unroll
          for (int j = 0; j < 4; ++j) {
            int rl = wr * 32 + m * 16 + q4 + j;
            o_rec[(size_t)(rowBase + rl) * 360 + col] = acc[m][n][j] + bb;
          }
        }
      }
  }
}

// ---------------------------------------------------------------------------
extern "C" void kernel_launch(void* const* d_in, const int* in_sizes, int n_in,
                              void* d_out, int out_size, void* d_ws,
                              size_t ws_size, hipStream_t stream) {
  (void)in_sizes; (void)n_in; (void)out_size; (void)ws_size;
  const float* x   = (const float*)d_in[0];
  const float* mc  = (const float*)d_in[2];
  const float* W1  = (const float*)d_in[3];  const float* b1  = (const float*)d_in[4];
  const float* W2  = (const float*)d_in[5];  const float* b2  = (const float*)d_in[6];
  const float* W3  = (const float*)d_in[7];
  const float* Wp1 = (const float*)d_in[9];  const float* bp1 = (const float*)d_in[10];
  const float* Wp2 = (const float*)d_in[11]; const float* bp2 = (const float*)d_in[12];
  const float* Wg1 = (const float*)d_in[13]; const float* bg1 = (const float*)d_in[14];
  const float* Wg2 = (const float*)d_in[15]; const float* bg2 = (const float*)d_in[16];
  const float* Wr1 = (const float*)d_in[17]; const float* br1 = (const float*)d_in[18];
  const float* Wr2 = (const float*)d_in[19]; const float* br2 = (const float*)d_in[20];

  float* out = (float*)d_out;
  float* o_znpi = out;                  // (B,128)
  float* o_zgeo = out + 2097152;        // (B,128)
  float* o_zn   = out + 4194304;        // (B,128)
  float* o_ec   = out + 6291456;        // (360,360)
  float* o_rec  = out + 6421056;        // (B,360)

  char* ws = (char*)d_ws;
  __bf16* m1T   = (__bf16*)(ws + 0);            // (256,16384)
  __bf16* m2T   = (__bf16*)(ws + 8388608);      // (256,16384)
  float*  G     = (float*)(ws + 16777216);      // 256x256
  float*  T     = (float*)(ws + 17039360);      // 256x384
  float*  p512  = (float*)(ws + 17432576);      // 512
  __bf16* W1p   = (__bf16*)(ws + 17434624);
  __bf16* W2p   = W1p  + (size_t)544 * 512;
  __bf16* Wg1p  = W2p  + (size_t)128 * 512;
  __bf16* Wg2p  = Wg1p + (size_t)112 * 512;
  __bf16* Wr1p  = Wg2p + (size_t)64 * 512;
  __bf16* Wr2p  = Wr1p + (size_t)64 * 512;
  int*    cnt   = (int*)(ws + 18565120);        // small_pair barrier counter

  pack_all<<<1136, 64, 0, stream>>>(W1, W2, Wg1, Wg2, Wr1, Wr2,
                                    W1p, W2p, Wg1p, Wg2p, Wr1p, Wr2p, G, cnt);
  h1h2_fused<<<512, 256, 0, stream>>>(x, W1p, b1, W2p, b2, m1T, m2T);
  gemm_masks<<<dim3(4, 4, 16), 256, 0, stream>>>(m2T, m1T, G);
  small_pair<<<36, 256, 0, stream>>>(W2, G, W1, W3, T, o_ec, cnt);
  p_and_g1<<<768, 512, 0, stream>>>(Wp1, o_ec, bp1, p512, mc, Wg1p, bg1,
                                    Wg2p, bg2, o_zgeo);
  mega_tail<<<256, 512, 0, stream>>>(p512, Wp2, bp2, o_zgeo, Wr1p, br1,
                                     Wr2p, br2, o_znpi, o_zn, o_rec);
}